// Round 1
// baseline (1256.907 us; speedup 1.0000x reference)
//
#include <hip/hip_runtime.h>
#include <hip/hip_bf16.h>
#include <math.h>

#define B_   128
#define T_   256
#define C_   384
#define H_   6
#define HS_  64
#define NTOK (B_*T_)   // 32768

// ---------------------------------------------------------------------------
// Kernel 1: QKV projection.  X[NTOK x C] @ W_ph[C x HS] for p in {q,k,v}, h in 0..5
// Output layout: q/k/v [B, H, T, HS]
// Grid: (NTOK/64, 3*H), block 256.  64x64 output tile, 4x4 microtile/thread.
// ---------------------------------------------------------------------------
__global__ __launch_bounds__(256) void qkv_gemm(
    const float* __restrict__ x,
    const float* __restrict__ Wq,
    const float* __restrict__ Wk,
    const float* __restrict__ Wv,
    float* __restrict__ q, float* __restrict__ k, float* __restrict__ v)
{
    __shared__ float xs[64][65];   // +1 pad: conflict-free column (a-frag) reads
    __shared__ float ws[64][64];   // row-major, b128-aligned rows

    const int mt = blockIdx.x;          // token tile
    const int pw = blockIdx.y;          // 0..17
    const int p  = pw / H_;
    const int h  = pw % H_;

    const float* W = (p == 0 ? Wq : (p == 1 ? Wk : Wv)) + h * C_ * HS_;
    float* outp    = (p == 0 ? q  : (p == 1 ? k  : v));

    const int n0  = mt * 64;
    const int tid = threadIdx.x;
    const int tx  = tid & 15;
    const int ty  = tid >> 4;

    float acc[4][4] = {};

    for (int k0 = 0; k0 < C_; k0 += 64) {
        #pragma unroll
        for (int e = tid; e < 64 * 64; e += 256) {
            const int r = e >> 6, c = e & 63;
            xs[r][c] = x[(n0 + r) * C_ + k0 + c];   // coalesced
            ws[r][c] = W[(k0 + r) * HS_ + c];       // coalesced (contiguous block)
        }
        __syncthreads();

        #pragma unroll 16
        for (int kk = 0; kk < 64; ++kk) {
            float a0 = xs[ty * 4 + 0][kk];
            float a1 = xs[ty * 4 + 1][kk];
            float a2 = xs[ty * 4 + 2][kk];
            float a3 = xs[ty * 4 + 3][kk];
            float b0 = ws[kk][tx * 4 + 0];
            float b1 = ws[kk][tx * 4 + 1];
            float b2 = ws[kk][tx * 4 + 2];
            float b3 = ws[kk][tx * 4 + 3];
            acc[0][0] = fmaf(a0, b0, acc[0][0]); acc[0][1] = fmaf(a0, b1, acc[0][1]);
            acc[0][2] = fmaf(a0, b2, acc[0][2]); acc[0][3] = fmaf(a0, b3, acc[0][3]);
            acc[1][0] = fmaf(a1, b0, acc[1][0]); acc[1][1] = fmaf(a1, b1, acc[1][1]);
            acc[1][2] = fmaf(a1, b2, acc[1][2]); acc[1][3] = fmaf(a1, b3, acc[1][3]);
            acc[2][0] = fmaf(a2, b0, acc[2][0]); acc[2][1] = fmaf(a2, b1, acc[2][1]);
            acc[2][2] = fmaf(a2, b2, acc[2][2]); acc[2][3] = fmaf(a2, b3, acc[2][3]);
            acc[3][0] = fmaf(a3, b0, acc[3][0]); acc[3][1] = fmaf(a3, b1, acc[3][1]);
            acc[3][2] = fmaf(a3, b2, acc[3][2]); acc[3][3] = fmaf(a3, b3, acc[3][3]);
        }
        __syncthreads();
    }

    #pragma unroll
    for (int i = 0; i < 4; ++i) {
        const int n  = n0 + ty * 4 + i;
        const int bb = n >> 8;          // n / T_
        const int tt = n & 255;         // n % T_
        float4 r4 = make_float4(acc[i][0], acc[i][1], acc[i][2], acc[i][3]);
        *(float4*)(outp + ((bb * H_ + h) * T_ + tt) * HS_ + tx * 4) = r4;
    }
}

// ---------------------------------------------------------------------------
// Kernel 2: causal attention with online softmax.
// Grid: (B*H), block 256 (one thread per query row t).
// K/V staged in LDS in 64-row tiles; q row + O accumulator in registers.
// Writes y[B, T, H*HS]  (head-concat layout).
// ---------------------------------------------------------------------------
__global__ __launch_bounds__(256) void attn_kernel(
    const float* __restrict__ q,
    const float* __restrict__ k,
    const float* __restrict__ v,
    float* __restrict__ y)
{
    __shared__ float ks[64][64];
    __shared__ float vs[64][64];

    const int bh = blockIdx.x;          // b*H + h
    const int b  = bh / H_;
    const int h  = bh % H_;
    const float* qb = q + (size_t)bh * T_ * HS_;
    const float* kb = k + (size_t)bh * T_ * HS_;
    const float* vb = v + (size_t)bh * T_ * HS_;

    const int t = threadIdx.x;          // query row

    float qr[HS_];
    #pragma unroll
    for (int i = 0; i < HS_ / 4; ++i) {
        float4 f = ((const float4*)(qb + t * HS_))[i];
        qr[4 * i + 0] = f.x; qr[4 * i + 1] = f.y;
        qr[4 * i + 2] = f.z; qr[4 * i + 3] = f.w;
    }

    float m = -INFINITY, l = 0.f;
    float o[HS_];
    #pragma unroll
    for (int d = 0; d < HS_; ++d) o[d] = 0.f;

    for (int j0 = 0; j0 < T_; j0 += 64) {
        __syncthreads();
        #pragma unroll
        for (int e = threadIdx.x; e < 64 * 64; e += 256) {
            const int s = e >> 6, d = e & 63;
            ks[s][d] = kb[(j0 + s) * HS_ + d];
            vs[s][d] = vb[(j0 + s) * HS_ + d];
        }
        __syncthreads();

        if (t >= j0) {                                // wave-uniform (t tiles align)
            const int send = min(t - j0, 63);
            for (int sl = 0; sl <= send; ++sl) {
                float dot = 0.f;
                #pragma unroll
                for (int d = 0; d < HS_; ++d) dot = fmaf(qr[d], ks[sl][d], dot);
                const float score = dot * 0.125f;     // 1/sqrt(64)
                const float mn    = fmaxf(m, score);
                const float corr  = __expf(m - mn);   // 0 when m==-inf
                const float e1    = __expf(score - mn);
                l = l * corr + e1;
                #pragma unroll
                for (int d = 0; d < HS_; ++d)
                    o[d] = fmaf(o[d], corr, e1 * vs[sl][d]);
                m = mn;
            }
        }
    }

    const float inv = 1.f / l;
    float* dst = y + ((size_t)(b * T_ + t)) * C_ + h * HS_;
    #pragma unroll
    for (int d4 = 0; d4 < HS_; d4 += 4) {
        float4 r4 = make_float4(o[d4] * inv, o[d4 + 1] * inv,
                                o[d4 + 2] * inv, o[d4 + 3] * inv);
        *(float4*)(dst + d4) = r4;
    }
}

// ---------------------------------------------------------------------------
// Kernel 3: output projection.  Y[NTOK x C] @ Wp^T [C x C] + bp
// out[n,i] = sum_j y[n,j] * Wp[i,j] + bp[i]
// Grid: (NTOK/64, C/64), block 256.
// ---------------------------------------------------------------------------
__global__ __launch_bounds__(256) void proj_gemm(
    const float* __restrict__ y,
    const float* __restrict__ Wp,
    const float* __restrict__ bp,
    float* __restrict__ out)
{
    __shared__ float xs[64][65];
    __shared__ float wpt[64][65];   // wpt[j][kk] = Wp[(c0+j)][k0+kk]

    const int mt = blockIdx.x;
    const int nt = blockIdx.y;
    const int n0 = mt * 64;
    const int c0 = nt * 64;
    const int tid = threadIdx.x;
    const int tx  = tid & 15;
    const int ty  = tid >> 4;

    float acc[4][4] = {};

    for (int k0 = 0; k0 < C_; k0 += 64) {
        #pragma unroll
        for (int e = tid; e < 64 * 64; e += 256) {
            const int r = e >> 6, c = e & 63;
            xs[r][c]  = y[(n0 + r) * C_ + k0 + c];        // coalesced
            wpt[r][c] = Wp[(c0 + r) * C_ + k0 + c];       // coalesced
        }
        __syncthreads();

        #pragma unroll 16
        for (int kk = 0; kk < 64; ++kk) {
            float a0 = xs[ty * 4 + 0][kk];
            float a1 = xs[ty * 4 + 1][kk];
            float a2 = xs[ty * 4 + 2][kk];
            float a3 = xs[ty * 4 + 3][kk];
            float b0 = wpt[tx * 4 + 0][kk];
            float b1 = wpt[tx * 4 + 1][kk];
            float b2 = wpt[tx * 4 + 2][kk];
            float b3 = wpt[tx * 4 + 3][kk];
            acc[0][0] = fmaf(a0, b0, acc[0][0]); acc[0][1] = fmaf(a0, b1, acc[0][1]);
            acc[0][2] = fmaf(a0, b2, acc[0][2]); acc[0][3] = fmaf(a0, b3, acc[0][3]);
            acc[1][0] = fmaf(a1, b0, acc[1][0]); acc[1][1] = fmaf(a1, b1, acc[1][1]);
            acc[1][2] = fmaf(a1, b2, acc[1][2]); acc[1][3] = fmaf(a1, b3, acc[1][3]);
            acc[2][0] = fmaf(a2, b0, acc[2][0]); acc[2][1] = fmaf(a2, b1, acc[2][1]);
            acc[2][2] = fmaf(a2, b2, acc[2][2]); acc[2][3] = fmaf(a2, b3, acc[2][3]);
            acc[3][0] = fmaf(a3, b0, acc[3][0]); acc[3][1] = fmaf(a3, b1, acc[3][1]);
            acc[3][2] = fmaf(a3, b2, acc[3][2]); acc[3][3] = fmaf(a3, b3, acc[3][3]);
        }
        __syncthreads();
    }

    #pragma unroll
    for (int i = 0; i < 4; ++i) {
        const int n = n0 + ty * 4 + i;
        #pragma unroll
        for (int j = 0; j < 4; ++j) {
            const int col = c0 + tx * 4 + j;
            out[n * C_ + col] = acc[i][j] + bp[col];
        }
    }
}

// ---------------------------------------------------------------------------
extern "C" void kernel_launch(void* const* d_in, const int* in_sizes, int n_in,
                              void* d_out, int out_size, void* d_ws, size_t ws_size,
                              hipStream_t stream)
{
    const float* x  = (const float*)d_in[0];
    const float* Wq = (const float*)d_in[1];
    const float* Wk = (const float*)d_in[2];
    const float* Wv = (const float*)d_in[3];
    const float* Wp = (const float*)d_in[4];
    const float* bp = (const float*)d_in[5];
    float* out = (float*)d_out;

    // workspace layout: q | k | v | y  (each NTOK*C/H... = B*H*T*HS = B*T*C floats)
    const size_t seg = (size_t)B_ * T_ * C_;   // 12,582,912 floats
    float* q = (float*)d_ws;
    float* k = q + seg;
    float* v = k + seg;
    float* y = v + seg;

    dim3 gA(NTOK / 64, 3 * H_);
    hipLaunchKernelGGL(qkv_gemm, gA, dim3(256), 0, stream, x, Wq, Wk, Wv, q, k, v);

    dim3 gB(B_ * H_);
    hipLaunchKernelGGL(attn_kernel, gB, dim3(256), 0, stream, q, k, v, y);

    dim3 gC(NTOK / 64, C_ / 64);
    hipLaunchKernelGGL(proj_gemm, gC, dim3(256), 0, stream, y, Wp, bp, out);
}

// Round 2
// 229.962 us; speedup vs baseline: 5.4657x; 5.4657x over previous
//
#include <hip/hip_runtime.h>
#include <hip/hip_bf16.h>
#include <math.h>

#define B_   128
#define T_   256
#define C_   384
#define H_   6
#define HS_  64
#define NTOK (B_*T_)          // 32768
#define NQKV (3*C_)           // 1152

typedef unsigned short u16;
typedef __attribute__((ext_vector_type(8))) short bf16x8;   // 8 bf16 in 4 VGPRs
typedef __attribute__((ext_vector_type(4))) float f32x4;

__device__ __forceinline__ u16 f2b(float f) {
    unsigned int u = __builtin_bit_cast(unsigned int, f);
    unsigned int r = (u + 0x7FFFu + ((u >> 16) & 1u)) >> 16;   // RNE
    return (u16)r;
}

// ---------------------------------------------------------------------------
// Prep: fp32 -> bf16 (vectorized, n must be multiple of 4)
// ---------------------------------------------------------------------------
__global__ __launch_bounds__(256) void cvt_bf16(const float* __restrict__ src,
                                                u16* __restrict__ dst, int n4)
{
    int i = blockIdx.x * 256 + threadIdx.x;
    if (i < n4) {
        float4 f = ((const float4*)src)[i];
        ushort4 o;
        o.x = f2b(f.x); o.y = f2b(f.y); o.z = f2b(f.z); o.w = f2b(f.w);
        ((ushort4*)dst)[i] = o;
    }
}

// ---------------------------------------------------------------------------
// Prep: build Wcat_t[n][c] bf16, n = p*384 + h*64 + d, value = W_p[h][c][d]
// ---------------------------------------------------------------------------
__global__ __launch_bounds__(256) void build_wcat(
    const float* __restrict__ Wq, const float* __restrict__ Wk,
    const float* __restrict__ Wv, u16* __restrict__ wct)
{
    int i = blockIdx.x * 256 + threadIdx.x;
    if (i >= NQKV * C_) return;
    int n = i / C_, c = i % C_;
    int p = n / C_, rem = n % C_;
    int h = rem >> 6, d = rem & 63;
    const float* W = (p == 0 ? Wq : (p == 1 ? Wk : Wv));
    wct[i] = f2b(W[(h * C_ + c) * HS_ + d]);
}

// ---------------------------------------------------------------------------
// Kernel 1: QKV GEMM, bf16 MFMA.  xb[32768x384] @ Wcat_t^T -> q,k,[b,h,t,d]; v transposed [b,h,d,t]
// Grid (256, 9), block 256 (4 waves), tile 128x128, BK=64, 16x16x32 MFMA.
// ---------------------------------------------------------------------------
__global__ __launch_bounds__(256) void gemm_qkv(
    const u16* __restrict__ xb,    // [NTOK][C_]
    const u16* __restrict__ wct,   // [NQKV][C_]
    u16* __restrict__ qo, u16* __restrict__ ko, u16* __restrict__ vt)
{
    __shared__ u16 As[128][72];
    __shared__ u16 Bs[128][72];

    const int tid = threadIdx.x;
    const int m0g = blockIdx.x * 128;
    const int n0g = blockIdx.y * 128;
    const int w = tid >> 6, lane = tid & 63;
    const int lm = lane & 15, qd = lane >> 4;
    const int wm = (w & 1) * 64, wn = (w >> 1) * 64;
    const int rr = tid >> 3, seg = tid & 7;

    f32x4 acc[4][4];
    #pragma unroll
    for (int mi = 0; mi < 4; ++mi)
        #pragma unroll
        for (int ni = 0; ni < 4; ++ni)
            acc[mi][ni] = (f32x4){0.f, 0.f, 0.f, 0.f};

    for (int k0 = 0; k0 < C_; k0 += 64) {
        __syncthreads();
        #pragma unroll
        for (int pp = 0; pp < 4; ++pp) {
            int row = rr + pp * 32;
            *(bf16x8*)&As[row][seg * 8] =
                *(const bf16x8*)(xb + (size_t)(m0g + row) * C_ + k0 + seg * 8);
            *(bf16x8*)&Bs[row][seg * 8] =
                *(const bf16x8*)(wct + (size_t)(n0g + row) * C_ + k0 + seg * 8);
        }
        __syncthreads();

        #pragma unroll
        for (int ks = 0; ks < 2; ++ks) {
            bf16x8 af[4], bfr[4];
            #pragma unroll
            for (int mi = 0; mi < 4; ++mi)
                af[mi] = *(const bf16x8*)&As[wm + mi * 16 + lm][ks * 32 + qd * 8];
            #pragma unroll
            for (int ni = 0; ni < 4; ++ni)
                bfr[ni] = *(const bf16x8*)&Bs[wn + ni * 16 + lm][ks * 32 + qd * 8];
            #pragma unroll
            for (int mi = 0; mi < 4; ++mi)
                #pragma unroll
                for (int ni = 0; ni < 4; ++ni)
                    acc[mi][ni] = __builtin_amdgcn_mfma_f32_16x16x32_bf16(
                        af[mi], bfr[ni], acc[mi][ni], 0, 0, 0);
        }
    }

    // Epilogue: C/D layout row = qd*4+reg, col = lm
    #pragma unroll
    for (int mi = 0; mi < 4; ++mi) {
        #pragma unroll
        for (int ni = 0; ni < 4; ++ni) {
            #pragma unroll
            for (int r = 0; r < 4; ++r) {
                int m = m0g + wm + mi * 16 + qd * 4 + r;
                int n = n0g + wn + ni * 16 + lm;
                int b = m >> 8, t = m & 255;
                int p = n / C_, rem = n % C_;
                int h = rem >> 6, d = rem & 63;
                u16 val = f2b(acc[mi][ni][r]);
                if (p == 0)
                    qo[((size_t)(b * H_ + h) * T_ + t) * HS_ + d] = val;
                else if (p == 1)
                    ko[((size_t)(b * H_ + h) * T_ + t) * HS_ + d] = val;
                else
                    vt[((size_t)(b * H_ + h) * HS_ + d) * T_ + t] = val;  // transposed
            }
        }
    }
}

// ---------------------------------------------------------------------------
// Kernel 2: flash attention, bf16 MFMA.
// Grid (B*H, 4): one (b,h) x 64-row q-tile per block; 4 waves x 16 q-rows.
// ---------------------------------------------------------------------------
__global__ __launch_bounds__(256) void attn_mfma(
    const u16* __restrict__ q, const u16* __restrict__ k,
    const u16* __restrict__ vt, u16* __restrict__ yb)
{
    __shared__ u16 Ks[64][72];        // [s][d]
    __shared__ u16 Vs[64][72];        // [d][s]  (v pre-transposed in global)
    __shared__ u16 Ps[4][16][72];     // per-wave P tile [t][s]

    const int bh = blockIdx.x;
    const int qt = blockIdx.y;
    const int b = bh / H_, h = bh % H_;
    const int tid = threadIdx.x, w = tid >> 6, lane = tid & 63;
    const int lm = lane & 15, qd = lane >> 4;
    const int t0w = qt * 64 + w * 16;
    const int rr = tid >> 3, seg = tid & 7;

    const u16* qb = q  + (size_t)bh * T_ * HS_;
    const u16* kb = k  + (size_t)bh * T_ * HS_;
    const u16* vb = vt + (size_t)bh * HS_ * T_;

    // Q A-fragments held in registers for the whole block
    bf16x8 aq[2];
    aq[0] = *(const bf16x8*)(qb + (size_t)(t0w + lm) * HS_ + qd * 8);
    aq[1] = *(const bf16x8*)(qb + (size_t)(t0w + lm) * HS_ + 32 + qd * 8);

    f32x4 acc[4];
    #pragma unroll
    for (int ni = 0; ni < 4; ++ni) acc[ni] = (f32x4){0.f, 0.f, 0.f, 0.f};
    float ms[4], ls[4];
    #pragma unroll
    for (int r = 0; r < 4; ++r) { ms[r] = -INFINITY; ls[r] = 0.f; }

    const int nkt = qt + 1;
    for (int kt = 0; kt < nkt; ++kt) {
        const int j0 = kt * 64;
        __syncthreads();
        #pragma unroll
        for (int pp = 0; pp < 2; ++pp) {
            int row = rr + pp * 32;
            *(bf16x8*)&Ks[row][seg * 8] =
                *(const bf16x8*)(kb + (size_t)(j0 + row) * HS_ + seg * 8);
            *(bf16x8*)&Vs[row][seg * 8] =
                *(const bf16x8*)(vb + (size_t)row * T_ + j0 + seg * 8);
        }
        __syncthreads();

        // S = Q K^T  (16 x 64 per wave)
        f32x4 st[4];
        #pragma unroll
        for (int ni = 0; ni < 4; ++ni) st[ni] = (f32x4){0.f, 0.f, 0.f, 0.f};
        #pragma unroll
        for (int ks = 0; ks < 2; ++ks) {
            #pragma unroll
            for (int ni = 0; ni < 4; ++ni) {
                bf16x8 bk = *(const bf16x8*)&Ks[ni * 16 + lm][ks * 32 + qd * 8];
                st[ni] = __builtin_amdgcn_mfma_f32_16x16x32_bf16(aq[ks], bk, st[ni], 0, 0, 0);
            }
        }

        // online softmax (rows = qd*4+r, cols = ni*16+lm)
        float vals[4][4], rowmax[4];
        #pragma unroll
        for (int r = 0; r < 4; ++r) rowmax[r] = -INFINITY;
        #pragma unroll
        for (int ni = 0; ni < 4; ++ni) {
            int s_g = j0 + ni * 16 + lm;
            #pragma unroll
            for (int r = 0; r < 4; ++r) {
                int t_g = t0w + qd * 4 + r;
                float sc = st[ni][r] * 0.125f;
                sc = (s_g > t_g) ? -1e30f : sc;
                vals[ni][r] = sc;
                rowmax[r] = fmaxf(rowmax[r], sc);
            }
        }
        #pragma unroll
        for (int msk = 1; msk <= 8; msk <<= 1)
            #pragma unroll
            for (int r = 0; r < 4; ++r)
                rowmax[r] = fmaxf(rowmax[r], __shfl_xor(rowmax[r], msk, 64));

        float corr[4], rowsum[4];
        #pragma unroll
        for (int r = 0; r < 4; ++r) {
            float mn = fmaxf(ms[r], rowmax[r]);
            corr[r] = __expf(ms[r] - mn);
            ms[r] = mn;
            rowsum[r] = 0.f;
        }
        float pvv[4][4];
        #pragma unroll
        for (int ni = 0; ni < 4; ++ni)
            #pragma unroll
            for (int r = 0; r < 4; ++r) {
                float p = __expf(vals[ni][r] - ms[r]);
                pvv[ni][r] = p;
                rowsum[r] += p;
            }
        #pragma unroll
        for (int msk = 1; msk <= 8; msk <<= 1)
            #pragma unroll
            for (int r = 0; r < 4; ++r)
                rowsum[r] += __shfl_xor(rowsum[r], msk, 64);
        #pragma unroll
        for (int r = 0; r < 4; ++r) ls[r] = ls[r] * corr[r] + rowsum[r];
        #pragma unroll
        for (int ni = 0; ni < 4; ++ni)
            #pragma unroll
            for (int r = 0; r < 4; ++r)
                acc[ni][r] *= corr[r];

        // P: C-layout regs -> LDS -> A-layout frags (m120 round-trip)
        #pragma unroll
        for (int ni = 0; ni < 4; ++ni)
            #pragma unroll
            for (int r = 0; r < 4; ++r)
                Ps[w][qd * 4 + r][ni * 16 + lm] = f2b(pvv[ni][r]);

        #pragma unroll
        for (int ks = 0; ks < 2; ++ks) {
            bf16x8 pa = *(const bf16x8*)&Ps[w][lm][ks * 32 + qd * 8];
            #pragma unroll
            for (int ni = 0; ni < 4; ++ni) {
                bf16x8 bv = *(const bf16x8*)&Vs[ni * 16 + lm][ks * 32 + qd * 8];
                acc[ni] = __builtin_amdgcn_mfma_f32_16x16x32_bf16(pa, bv, acc[ni], 0, 0, 0);
            }
        }
    }

    // epilogue: yb[b*T+t][h*64 + d] bf16
    #pragma unroll
    for (int r = 0; r < 4; ++r) {
        float inv = 1.f / ls[r];
        int t_g = t0w + qd * 4 + r;
        #pragma unroll
        for (int ni = 0; ni < 4; ++ni) {
            int col = h * HS_ + ni * 16 + lm;
            yb[((size_t)(b * T_ + t_g)) * C_ + col] = f2b(acc[ni][r] * inv);
        }
    }
}

// ---------------------------------------------------------------------------
// Kernel 3: output projection, bf16 MFMA.  yb[32768x384] @ wpb^T + bp -> fp32
// Grid (256, 3), block 256, tile 128x128.
// ---------------------------------------------------------------------------
__global__ __launch_bounds__(256) void gemm_proj(
    const u16* __restrict__ yb,    // [NTOK][C_]
    const u16* __restrict__ wpb,   // [C_][C_]  (row i = out col, col j = k)
    const float* __restrict__ bp,
    float* __restrict__ out)
{
    __shared__ u16 As[128][72];
    __shared__ u16 Bs[128][72];

    const int tid = threadIdx.x;
    const int m0g = blockIdx.x * 128;
    const int n0g = blockIdx.y * 128;
    const int w = tid >> 6, lane = tid & 63;
    const int lm = lane & 15, qd = lane >> 4;
    const int wm = (w & 1) * 64, wn = (w >> 1) * 64;
    const int rr = tid >> 3, seg = tid & 7;

    f32x4 acc[4][4];
    #pragma unroll
    for (int mi = 0; mi < 4; ++mi)
        #pragma unroll
        for (int ni = 0; ni < 4; ++ni)
            acc[mi][ni] = (f32x4){0.f, 0.f, 0.f, 0.f};

    for (int k0 = 0; k0 < C_; k0 += 64) {
        __syncthreads();
        #pragma unroll
        for (int pp = 0; pp < 4; ++pp) {
            int row = rr + pp * 32;
            *(bf16x8*)&As[row][seg * 8] =
                *(const bf16x8*)(yb + (size_t)(m0g + row) * C_ + k0 + seg * 8);
            *(bf16x8*)&Bs[row][seg * 8] =
                *(const bf16x8*)(wpb + (size_t)(n0g + row) * C_ + k0 + seg * 8);
        }
        __syncthreads();

        #pragma unroll
        for (int ks = 0; ks < 2; ++ks) {
            bf16x8 af[4], bfr[4];
            #pragma unroll
            for (int mi = 0; mi < 4; ++mi)
                af[mi] = *(const bf16x8*)&As[wm + mi * 16 + lm][ks * 32 + qd * 8];
            #pragma unroll
            for (int ni = 0; ni < 4; ++ni)
                bfr[ni] = *(const bf16x8*)&Bs[wn + ni * 16 + lm][ks * 32 + qd * 8];
            #pragma unroll
            for (int mi = 0; mi < 4; ++mi)
                #pragma unroll
                for (int ni = 0; ni < 4; ++ni)
                    acc[mi][ni] = __builtin_amdgcn_mfma_f32_16x16x32_bf16(
                        af[mi], bfr[ni], acc[mi][ni], 0, 0, 0);
        }
    }

    #pragma unroll
    for (int mi = 0; mi < 4; ++mi) {
        #pragma unroll
        for (int ni = 0; ni < 4; ++ni) {
            #pragma unroll
            for (int r = 0; r < 4; ++r) {
                int m = m0g + wm + mi * 16 + qd * 4 + r;
                int n = n0g + wn + ni * 16 + lm;
                out[(size_t)m * C_ + n] = acc[mi][ni][r] + bp[n];
            }
        }
    }
}

// ---------------------------------------------------------------------------
extern "C" void kernel_launch(void* const* d_in, const int* in_sizes, int n_in,
                              void* d_out, int out_size, void* d_ws, size_t ws_size,
                              hipStream_t stream)
{
    const float* x  = (const float*)d_in[0];
    const float* Wq = (const float*)d_in[1];
    const float* Wk = (const float*)d_in[2];
    const float* Wv = (const float*)d_in[3];
    const float* Wp = (const float*)d_in[4];
    const float* bp = (const float*)d_in[5];
    float* out = (float*)d_out;

    // workspace layout (u16 elements)
    u16* xb  = (u16*)d_ws;                         // 32768*384
    u16* wct = xb  + (size_t)NTOK * C_;            // 1152*384
    u16* wpb = wct + (size_t)NQKV * C_;            // 384*384
    u16* qo  = wpb + (size_t)C_ * C_;              // B*H*T*HS
    u16* ko  = qo  + (size_t)B_ * H_ * T_ * HS_;
    u16* vt  = ko  + (size_t)B_ * H_ * T_ * HS_;
    u16* yb  = vt  + (size_t)B_ * H_ * T_ * HS_;   // 32768*384

    // prep
    hipLaunchKernelGGL(cvt_bf16, dim3((NTOK * C_ / 4 + 255) / 256), dim3(256), 0, stream,
                       x, xb, NTOK * C_ / 4);
    hipLaunchKernelGGL(build_wcat, dim3((NQKV * C_ + 255) / 256), dim3(256), 0, stream,
                       Wq, Wk, Wv, wct);
    hipLaunchKernelGGL(cvt_bf16, dim3((C_ * C_ / 4 + 255) / 256), dim3(256), 0, stream,
                       Wp, wpb, C_ * C_ / 4);

    // QKV projection
    hipLaunchKernelGGL(gemm_qkv, dim3(NTOK / 128, NQKV / 128), dim3(256), 0, stream,
                       xb, wct, qo, ko, vt);

    // attention
    hipLaunchKernelGGL(attn_mfma, dim3(B_ * H_, T_ / 64), dim3(256), 0, stream,
                       qo, ko, vt, yb);

    // output projection
    hipLaunchKernelGGL(gemm_proj, dim3(NTOK / 128, C_ / 128), dim3(256), 0, stream,
                       yb, wpb, bp, out);
}

// Round 3
// 212.675 us; speedup vs baseline: 5.9100x; 1.0813x over previous
//
#include <hip/hip_runtime.h>
#include <hip/hip_bf16.h>
#include <math.h>

#define B_   128
#define T_   256
#define C_   384
#define H_   6
#define HS_  64
#define NTOK (B_*T_)          // 32768
#define NQKV (3*C_)           // 1152

typedef unsigned short u16;
typedef __attribute__((ext_vector_type(8))) short bf16x8;   // 8 bf16 in 4 VGPRs
typedef __attribute__((ext_vector_type(4))) float f32x4;

__device__ __forceinline__ u16 f2b(float f) {
    unsigned int u = __builtin_bit_cast(unsigned int, f);
    unsigned int r = (u + 0x7FFFu + ((u >> 16) & 1u)) >> 16;   // RNE
    return (u16)r;
}

// async global->LDS, 16B per lane.  LDS dst = wave-uniform base + lane*16B.
__device__ __forceinline__ void gl2lds16(const u16* g, u16* l) {
    __builtin_amdgcn_global_load_lds(
        (const __attribute__((address_space(1))) unsigned int*)g,
        (__attribute__((address_space(3))) unsigned int*)l, 16, 0, 0);
}

// ---------------------------------------------------------------------------
// Fused prep: x->bf16 (8/thread), Wp->bf16 (8/thread), Wcat_t build (1/thread)
// ---------------------------------------------------------------------------
#define J0_ (NTOK*C_/8)     // 1,572,864
#define J2_ (C_*C_/8)       // 18,432
#define J1_ (NQKV*C_)       // 442,368

__global__ __launch_bounds__(256) void prep(
    const float* __restrict__ x,  const float* __restrict__ Wq,
    const float* __restrict__ Wk, const float* __restrict__ Wv,
    const float* __restrict__ Wp,
    u16* __restrict__ xb, u16* __restrict__ wct, u16* __restrict__ wpb)
{
    int i = blockIdx.x * 256 + threadIdx.x;
    if (i < J0_) {
        const float4* s = (const float4*)x + (size_t)i * 2;
        float4 a = s[0], b = s[1];
        ushort4 o1, o2;
        o1.x = f2b(a.x); o1.y = f2b(a.y); o1.z = f2b(a.z); o1.w = f2b(a.w);
        o2.x = f2b(b.x); o2.y = f2b(b.y); o2.z = f2b(b.z); o2.w = f2b(b.w);
        ((ushort4*)xb)[(size_t)i * 2]     = o1;
        ((ushort4*)xb)[(size_t)i * 2 + 1] = o2;
    } else if (i < J0_ + J2_) {
        int j = i - J0_;
        const float4* s = (const float4*)Wp + (size_t)j * 2;
        float4 a = s[0], b = s[1];
        ushort4 o1, o2;
        o1.x = f2b(a.x); o1.y = f2b(a.y); o1.z = f2b(a.z); o1.w = f2b(a.w);
        o2.x = f2b(b.x); o2.y = f2b(b.y); o2.z = f2b(b.z); o2.w = f2b(b.w);
        ((ushort4*)wpb)[(size_t)j * 2]     = o1;
        ((ushort4*)wpb)[(size_t)j * 2 + 1] = o2;
    } else {
        int j = i - J0_ - J2_;
        if (j < J1_) {
            int n = j / C_, c = j % C_;
            int p = n / C_, rem = n % C_;
            int h = rem >> 6, d = rem & 63;
            const float* W = (p == 0 ? Wq : (p == 1 ? Wk : Wv));
            wct[j] = f2b(W[(h * C_ + c) * HS_ + d]);
        }
    }
}

// ---------------------------------------------------------------------------
// Kernel 1: QKV GEMM.  xb[32768x384] @ wct^T.  q scaled by 0.125.
// q,k -> [b,h,t,d]; v -> [b,h,d,t] (transposed, packed 8B stores).
// Grid (256, 9), block 256.  global_load_lds + XOR-swizzled LDS.
// ---------------------------------------------------------------------------
__global__ __launch_bounds__(256) void gemm_qkv(
    const u16* __restrict__ xb, const u16* __restrict__ wct,
    u16* __restrict__ qo, u16* __restrict__ ko, u16* __restrict__ vt)
{
    __shared__ __align__(16) u16 As[128 * 64];
    __shared__ __align__(16) u16 Bs[128 * 64];

    const int tid = threadIdx.x;
    const int m0g = blockIdx.x * 128;
    const int n0g = blockIdx.y * 128;
    const int w = tid >> 6, lane = tid & 63;
    const int lm = lane & 15, qd = lane >> 4;
    const int wm = (w & 1) * 64, wn = (w >> 1) * 64;

    // staging: wave w covers rows w*32..w*32+31 (4 insts x 8 rows)
    const int srow   = w * 32 + (lane >> 3);
    const int schunk = (lane & 7) ^ ((lane >> 3) & 7);   // XOR swizzle
    const u16* gA = xb  + (size_t)(m0g + srow) * C_ + schunk * 8;
    const u16* gB = wct + (size_t)(n0g + srow) * C_ + schunk * 8;
    u16* lA = &As[(w * 32) * 64];
    u16* lB = &Bs[(w * 32) * 64];

    f32x4 acc[4][4];
    #pragma unroll
    for (int mi = 0; mi < 4; ++mi)
        #pragma unroll
        for (int ni = 0; ni < 4; ++ni)
            acc[mi][ni] = (f32x4){0.f, 0.f, 0.f, 0.f};

    for (int k0 = 0; k0 < C_; k0 += 64) {
        __syncthreads();
        #pragma unroll
        for (int j = 0; j < 4; ++j) {
            gl2lds16(gA + j * 8 * C_, lA + j * 8 * 64);
            gl2lds16(gB + j * 8 * C_, lB + j * 8 * 64);
        }
        gA += 64; gB += 64;
        __syncthreads();   // vmcnt(0) drain of global_load_lds

        #pragma unroll
        for (int ks = 0; ks < 2; ++ks) {
            bf16x8 af[4], bfr[4];
            #pragma unroll
            for (int mi = 0; mi < 4; ++mi) {
                const int row = wm + mi * 16 + lm;
                const int sl = (ks * 4 + qd) ^ (lm & 7);
                af[mi] = *(const bf16x8*)&As[row * 64 + sl * 8];
            }
            #pragma unroll
            for (int ni = 0; ni < 4; ++ni) {
                const int row = wn + ni * 16 + lm;
                const int sl = (ks * 4 + qd) ^ (lm & 7);
                bfr[ni] = *(const bf16x8*)&Bs[row * 64 + sl * 8];
            }
            #pragma unroll
            for (int mi = 0; mi < 4; ++mi)
                #pragma unroll
                for (int ni = 0; ni < 4; ++ni)
                    acc[mi][ni] = __builtin_amdgcn_mfma_f32_16x16x32_bf16(
                        af[mi], bfr[ni], acc[mi][ni], 0, 0, 0);
        }
    }

    const int bI = m0g >> 8;
    const int tBase = (m0g & 255) + wm;
    const int yb_ = blockIdx.y;

    if (yb_ < 6) {                                   // q or k: [b,h,t,d]
        u16* dst = (yb_ < 3) ? qo : ko;
        const float scl = (yb_ < 3) ? 0.125f : 1.0f;  // fold 1/sqrt(HS) into q
        #pragma unroll
        for (int mi = 0; mi < 4; ++mi) {
            #pragma unroll
            for (int ni = 0; ni < 4; ++ni) {
                const int nn = n0g + wn + ni * 16 + lm - ((yb_ < 3) ? 0 : 384);
                const int h = nn >> 6, d = nn & 63;
                #pragma unroll
                for (int r = 0; r < 4; ++r) {
                    const int t = tBase + mi * 16 + qd * 4 + r;
                    dst[((size_t)(bI * H_ + h) * T_ + t) * HS_ + d]
                        = f2b(acc[mi][ni][r] * scl);
                }
            }
        }
    } else {                                         // v: [b,h,d,t], 4 t's packed
        #pragma unroll
        for (int mi = 0; mi < 4; ++mi) {
            #pragma unroll
            for (int ni = 0; ni < 4; ++ni) {
                const int nn = n0g + wn + ni * 16 + lm - 768;
                const int h = nn >> 6, d = nn & 63;
                const int t0 = tBase + mi * 16 + qd * 4;
                ushort4 sv;
                sv.x = f2b(acc[mi][ni][0]); sv.y = f2b(acc[mi][ni][1]);
                sv.z = f2b(acc[mi][ni][2]); sv.w = f2b(acc[mi][ni][3]);
                *(ushort4*)(vt + ((size_t)(bI * H_ + h) * HS_ + d) * T_ + t0) = sv;
            }
        }
    }
}

// ---------------------------------------------------------------------------
// Kernel 2: flash attention.  Grid (B*H, T/128), block 256.
// Each wave: 2 row-groups of 16 q-rows (rg*64 apart).  q pre-scaled.
// ---------------------------------------------------------------------------
__global__ __launch_bounds__(256) void attn_mfma(
    const u16* __restrict__ q, const u16* __restrict__ k,
    const u16* __restrict__ vt, u16* __restrict__ yb)
{
    __shared__ __align__(16) u16 Ks[64 * 64];
    __shared__ __align__(16) u16 Vs[64 * 64];
    __shared__ __align__(16) u16 Ps[4][2][16 * 72];

    const int bh = blockIdx.x;
    const int qt = blockIdx.y;
    const int b = bh / H_, h = bh % H_;
    const int tid = threadIdx.x, w = tid >> 6, lane = tid & 63;
    const int lm = lane & 15, qd = lane >> 4;

    const u16* qb = q  + (size_t)bh * T_ * HS_;
    const u16* kb = k  + (size_t)bh * T_ * HS_;
    const u16* vb = vt + (size_t)bh * HS_ * T_;

    const int t0 = qt * 128 + w * 16;

    bf16x8 aq[2][2];
    #pragma unroll
    for (int rg = 0; rg < 2; ++rg) {
        const u16* qrow = qb + (size_t)(t0 + rg * 64 + lm) * HS_;
        aq[rg][0] = *(const bf16x8*)(qrow + qd * 8);
        aq[rg][1] = *(const bf16x8*)(qrow + 32 + qd * 8);
    }

    f32x4 acc[2][4];
    float ms[2][4], ls[2][4];
    #pragma unroll
    for (int rg = 0; rg < 2; ++rg) {
        #pragma unroll
        for (int ni = 0; ni < 4; ++ni) acc[rg][ni] = (f32x4){0.f, 0.f, 0.f, 0.f};
        #pragma unroll
        for (int r = 0; r < 4; ++r) { ms[rg][r] = -INFINITY; ls[rg][r] = 0.f; }
    }

    // staging: wave w covers rows w*16..w*16+15 (2 insts x 8 rows)
    const int srow   = w * 16 + (lane >> 3);
    const int schunk = (lane & 7) ^ ((lane >> 3) & 7);
    const u16* gK = kb + (size_t)srow * HS_ + schunk * 8;
    const u16* gV = vb + (size_t)srow * T_  + schunk * 8;
    u16* lK = &Ks[(w * 16) * 64];
    u16* lV = &Vs[(w * 16) * 64];

    const int nkt = (qt + 1) * 2;
    for (int kt = 0; kt < nkt; ++kt) {
        const int j0 = kt * 64;
        __syncthreads();
        #pragma unroll
        for (int j = 0; j < 2; ++j) {
            gl2lds16(gK + j * 8 * HS_, lK + j * 8 * 64);
            gl2lds16(gV + j * 8 * T_,  lV + j * 8 * 64);
        }
        gK += (size_t)64 * HS_;
        gV += 64;
        __syncthreads();

        #pragma unroll
        for (int rg = 0; rg < 2; ++rg) {
            const int trg = t0 + rg * 64;
            if (j0 > trg + 15) continue;             // fully masked (wave-uniform)
            const bool needmask = (j0 + 63 > trg);

            // S = Q K^T  (16 x 64)
            f32x4 st[4];
            #pragma unroll
            for (int ni = 0; ni < 4; ++ni) st[ni] = (f32x4){0.f, 0.f, 0.f, 0.f};
            #pragma unroll
            for (int ks = 0; ks < 2; ++ks) {
                #pragma unroll
                for (int ni = 0; ni < 4; ++ni) {
                    const int sl = (ks * 4 + qd) ^ (lm & 7);
                    bf16x8 bk = *(const bf16x8*)&Ks[(ni * 16 + lm) * 64 + sl * 8];
                    st[ni] = __builtin_amdgcn_mfma_f32_16x16x32_bf16(
                        aq[rg][ks], bk, st[ni], 0, 0, 0);
                }
            }

            // online softmax
            float vals[4][4], rowmax[4];
            #pragma unroll
            for (int r = 0; r < 4; ++r) rowmax[r] = -INFINITY;
            #pragma unroll
            for (int ni = 0; ni < 4; ++ni) {
                const int s_g = j0 + ni * 16 + lm;
                #pragma unroll
                for (int r = 0; r < 4; ++r) {
                    float sc = st[ni][r];
                    if (needmask) {
                        const int t_g = trg + qd * 4 + r;
                        sc = (s_g > t_g) ? -1e30f : sc;
                    }
                    vals[ni][r] = sc;
                    rowmax[r] = fmaxf(rowmax[r], sc);
                }
            }
            #pragma unroll
            for (int msk = 1; msk <= 8; msk <<= 1)
                #pragma unroll
                for (int r = 0; r < 4; ++r)
                    rowmax[r] = fmaxf(rowmax[r], __shfl_xor(rowmax[r], msk, 64));

            float corr[4], rowsum[4];
            #pragma unroll
            for (int r = 0; r < 4; ++r) {
                const float mn = fmaxf(ms[rg][r], rowmax[r]);
                corr[r] = __expf(ms[rg][r] - mn);
                ms[rg][r] = mn;
                rowsum[r] = 0.f;
            }
            u16* Pw = &Ps[w][rg][0];
            #pragma unroll
            for (int ni = 0; ni < 4; ++ni) {
                #pragma unroll
                for (int r = 0; r < 4; ++r) {
                    const float p = __expf(vals[ni][r] - ms[rg][r]);
                    rowsum[r] += p;
                    Pw[(qd * 4 + r) * 72 + ni * 16 + lm] = f2b(p);
                }
            }
            #pragma unroll
            for (int msk = 1; msk <= 8; msk <<= 1)
                #pragma unroll
                for (int r = 0; r < 4; ++r)
                    rowsum[r] += __shfl_xor(rowsum[r], msk, 64);
            #pragma unroll
            for (int r = 0; r < 4; ++r) ls[rg][r] = ls[rg][r] * corr[r] + rowsum[r];
            #pragma unroll
            for (int ni = 0; ni < 4; ++ni)
                #pragma unroll
                for (int r = 0; r < 4; ++r)
                    acc[rg][ni][r] *= corr[r];

            // PV (P via per-wave LDS; DS pipe is in-order per wave)
            #pragma unroll
            for (int ks = 0; ks < 2; ++ks) {
                bf16x8 pa = *(const bf16x8*)&Pw[lm * 72 + ks * 32 + qd * 8];
                #pragma unroll
                for (int ni = 0; ni < 4; ++ni) {
                    const int sl = (ks * 4 + qd) ^ (lm & 7);
                    bf16x8 bv = *(const bf16x8*)&Vs[(ni * 16 + lm) * 64 + sl * 8];
                    acc[rg][ni] = __builtin_amdgcn_mfma_f32_16x16x32_bf16(
                        pa, bv, acc[rg][ni], 0, 0, 0);
                }
            }
        }
    }

    #pragma unroll
    for (int rg = 0; rg < 2; ++rg) {
        #pragma unroll
        for (int r = 0; r < 4; ++r) {
            const float inv = 1.f / ls[rg][r];
            const int t_g = t0 + rg * 64 + qd * 4 + r;
            #pragma unroll
            for (int ni = 0; ni < 4; ++ni) {
                const int col = h * HS_ + ni * 16 + lm;
                yb[((size_t)(b * T_ + t_g)) * C_ + col] = f2b(acc[rg][ni][r] * inv);
            }
        }
    }
}

// ---------------------------------------------------------------------------
// Kernel 3: output projection.  yb[32768x384] @ wpb^T + bp -> fp32 out.
// Grid (256, 3), block 256.  Same structure as gemm_qkv.
// ---------------------------------------------------------------------------
__global__ __launch_bounds__(256) void gemm_proj(
    const u16* __restrict__ yb, const u16* __restrict__ wpb,
    const float* __restrict__ bp, float* __restrict__ out)
{
    __shared__ __align__(16) u16 As[128 * 64];
    __shared__ __align__(16) u16 Bs[128 * 64];

    const int tid = threadIdx.x;
    const int m0g = blockIdx.x * 128;
    const int n0g = blockIdx.y * 128;
    const int w = tid >> 6, lane = tid & 63;
    const int lm = lane & 15, qd = lane >> 4;
    const int wm = (w & 1) * 64, wn = (w >> 1) * 64;

    const int srow   = w * 32 + (lane >> 3);
    const int schunk = (lane & 7) ^ ((lane >> 3) & 7);
    const u16* gA = yb  + (size_t)(m0g + srow) * C_ + schunk * 8;
    const u16* gB = wpb + (size_t)(n0g + srow) * C_ + schunk * 8;
    u16* lA = &As[(w * 32) * 64];
    u16* lB = &Bs[(w * 32) * 64];

    f32x4 acc[4][4];
    #pragma unroll
    for (int mi = 0; mi < 4; ++mi)
        #pragma unroll
        for (int ni = 0; ni < 4; ++ni)
            acc[mi][ni] = (f32x4){0.f, 0.f, 0.f, 0.f};

    for (int k0 = 0; k0 < C_; k0 += 64) {
        __syncthreads();
        #pragma unroll
        for (int j = 0; j < 4; ++j) {
            gl2lds16(gA + j * 8 * C_, lA + j * 8 * 64);
            gl2lds16(gB + j * 8 * C_, lB + j * 8 * 64);
        }
        gA += 64; gB += 64;
        __syncthreads();

        #pragma unroll
        for (int ks = 0; ks < 2; ++ks) {
            bf16x8 af[4], bfr[4];
            #pragma unroll
            for (int mi = 0; mi < 4; ++mi) {
                const int row = wm + mi * 16 + lm;
                const int sl = (ks * 4 + qd) ^ (lm & 7);
                af[mi] = *(const bf16x8*)&As[row * 64 + sl * 8];
            }
            #pragma unroll
            for (int ni = 0; ni < 4; ++ni) {
                const int row = wn + ni * 16 + lm;
                const int sl = (ks * 4 + qd) ^ (lm & 7);
                bfr[ni] = *(const bf16x8*)&Bs[row * 64 + sl * 8];
            }
            #pragma unroll
            for (int mi = 0; mi < 4; ++mi)
                #pragma unroll
                for (int ni = 0; ni < 4; ++ni)
                    acc[mi][ni] = __builtin_amdgcn_mfma_f32_16x16x32_bf16(
                        af[mi], bfr[ni], acc[mi][ni], 0, 0, 0);
        }
    }

    #pragma unroll
    for (int mi = 0; mi < 4; ++mi) {
        #pragma unroll
        for (int ni = 0; ni < 4; ++ni) {
            const int n = n0g + wn + ni * 16 + lm;
            const float bpv = bp[n];
            #pragma unroll
            for (int r = 0; r < 4; ++r) {
                const int m = m0g + wm + mi * 16 + qd * 4 + r;
                out[(size_t)m * C_ + n] = acc[mi][ni][r] + bpv;
            }
        }
    }
}

// ---------------------------------------------------------------------------
extern "C" void kernel_launch(void* const* d_in, const int* in_sizes, int n_in,
                              void* d_out, int out_size, void* d_ws, size_t ws_size,
                              hipStream_t stream)
{
    const float* x  = (const float*)d_in[0];
    const float* Wq = (const float*)d_in[1];
    const float* Wk = (const float*)d_in[2];
    const float* Wv = (const float*)d_in[3];
    const float* Wp = (const float*)d_in[4];
    const float* bp = (const float*)d_in[5];
    float* out = (float*)d_out;

    u16* xb  = (u16*)d_ws;                         // 32768*384
    u16* wct = xb  + (size_t)NTOK * C_;            // 1152*384
    u16* wpb = wct + (size_t)NQKV * C_;            // 384*384
    u16* qo  = wpb + (size_t)C_ * C_;
    u16* ko  = qo  + (size_t)B_ * H_ * T_ * HS_;
    u16* vt  = ko  + (size_t)B_ * H_ * T_ * HS_;
    u16* yb  = vt  + (size_t)B_ * H_ * T_ * HS_;

    const int prep_blocks = (J0_ + J2_ + J1_ + 255) / 256;
    hipLaunchKernelGGL(prep, dim3(prep_blocks), dim3(256), 0, stream,
                       x, Wq, Wk, Wv, Wp, xb, wct, wpb);

    hipLaunchKernelGGL(gemm_qkv, dim3(NTOK / 128, NQKV / 128), dim3(256), 0, stream,
                       xb, wct, qo, ko, vt);

    hipLaunchKernelGGL(attn_mfma, dim3(B_ * H_, T_ / 128), dim3(256), 0, stream,
                       qo, ko, vt, yb);

    hipLaunchKernelGGL(gemm_proj, dim3(NTOK / 128, C_ / 128), dim3(256), 0, stream,
                       yb, wpb, bp, out);
}